// Round 3
// baseline (137.617 us; speedup 1.0000x reference)
//
#include <hip/hip_runtime.h>

// LimbLength: out[b,k] = || in[b,k,:] - in[b,parent[k],:] ||_2
// in: (B=500000, K=15, D=3) float32, out: (B,15,1) float32.
// Memory-bound floor: 90 MB read + 30 MB write ~= 19 us @ 6.3 TB/s.
//
// v2b: stage 64 bodies/block (720 x 16B = 11520 B) into LDS with coalesced
// 16B/lane non-temporal loads; one thread per output element computes from
// LDS (stride-3 access -> <=2-way bank aliasing, free on gfx950 per m136).
// Stores are contiguous scalar floats (wave writes 256 B runs), non-temporal.
// (v2 failed to compile: __builtin_nontemporal_load rejects HIP_vector_type
// float4 -> use a clang ext_vector_type instead.)

typedef float f32x4 __attribute__((ext_vector_type(4)));

// LIMB_CONNECTION = [0,0,1,1,1,3,4,5,6,2,2,9,10,11,12] packed 4 bits/entry.
#define LIMB_PACK 0x0CBA922654311100ULL

#define BODIES_PER_BLOCK 64
#define BLOCK_THREADS    960   // 15 waves; one output per thread
#define F4_PER_BLOCK     720   // 64 bodies * 45 floats / 4

__global__ __launch_bounds__(BLOCK_THREADS) void limb_length_v2(
    const f32x4* __restrict__ in4, float* __restrict__ out,
    int n_body, int n_float4) {
    __shared__ float lds[BODIES_PER_BLOCK * 45];  // 11520 B

    const int tid = threadIdx.x;
    const int blk = blockIdx.x;

    // Stage 64 rows into LDS: threads 0..719 each load one 16B chunk.
    if (tid < F4_PER_BLOCK) {
        int gi = blk * F4_PER_BLOCK + tid;
        if (gi < n_float4) {
            f32x4 v = __builtin_nontemporal_load(&in4[gi]);
            ((f32x4*)lds)[tid] = v;
        }
    }
    __syncthreads();

    const unsigned ut = (unsigned)tid;
    const unsigned lb = ut / 15u;          // local body (const-divisor -> mulhi)
    const unsigned k  = ut - lb * 15u;     // joint index
    const int body = blk * BODIES_PER_BLOCK + (int)lb;
    if (body >= n_body) return;

    const unsigned p = (unsigned)((LIMB_PACK >> (k * 4u)) & 0xFULL);
    const float* __restrict__ row = lds + lb * 45u;
    const float dx = row[k * 3u + 0u] - row[p * 3u + 0u];
    const float dy = row[k * 3u + 1u] - row[p * 3u + 1u];
    const float dz = row[k * 3u + 2u] - row[p * 3u + 2u];

    // out[body*15 + k] == blk*960 + tid (contiguous per block)
    __builtin_nontemporal_store(sqrtf(dx * dx + dy * dy + dz * dz),
                                &out[blk * BLOCK_THREADS + tid]);
}

extern "C" void kernel_launch(void* const* d_in, const int* in_sizes, int n_in,
                              void* d_out, int out_size, void* d_ws, size_t ws_size,
                              hipStream_t stream) {
    const f32x4* in4 = (const f32x4*)d_in[0];
    float* out = (float*)d_out;
    const int n_body = out_size / 15;                 // 500000
    const int n_float4 = in_sizes[0] / 4;             // 22.5M floats / 4
    const int grid = (n_body + BODIES_PER_BLOCK - 1) / BODIES_PER_BLOCK;
    limb_length_v2<<<grid, BLOCK_THREADS, 0, stream>>>(in4, out, n_body, n_float4);
}